// Round 1
// baseline (7241.862 us; speedup 1.0000x reference)
//
#include <hip/hip_runtime.h>

#define B_TOT 16384
#define T_STEPS 40
#define HDIM 100
#define G4 400
#define BT 32
#define NTHREADS 128

typedef __attribute__((ext_vector_type(4))) float f32x4;
typedef __attribute__((ext_vector_type(2))) float f32x2;

__device__ __forceinline__ float sigf(float x) {
    return 1.0f / (1.0f + __expf(-x));
}
__device__ __forceinline__ float tanh_fast(float x) {
    // 2*sigmoid(2x)-1 ; safe at extremes (no NaN): exp->inf => 0, exp->0 => 1
    return 2.0f / (1.0f + __expf(-2.0f * x)) - 1.0f;
}

__global__ __launch_bounds__(NTHREADS, 1)
void fwdsim_kernel(const float* __restrict__ sampled_z,
                   const float* __restrict__ idm_s,
                   const float* __restrict__ sdv_acts,
                   const float* __restrict__ W1, const float* __restrict__ b1,
                   const float* __restrict__ W2, const float* __restrict__ b2,
                   const float* __restrict__ Wk, const float* __restrict__ Wr,
                   const float* __restrict__ bl,
                   const float* __restrict__ Wd, const float* __restrict__ bd,
                   const float* __restrict__ sc_mean, const float* __restrict__ sc_var,
                   float* __restrict__ out, float* __restrict__ gk_ws)
{
    __shared__ float z_s[BT][G4];     // 51.2 KB : z exchange (also h1 scratch)
    __shared__ float h_s[BT][HDIM];   // 12.8 KB : recurrent h
    __shared__ float wk_s[9 * G4];    // 14.4 KB : Wk rows 100..108 (sdv+env)

    const int tid = threadIdx.x;
    const int e   = tid >> 2;      // 0..31 local batch element
    const int q   = tid & 3;       // 0..3  column quarter
    const int j0  = q * 100;
    const int eg  = blockIdx.x * BT + e;

    // ---- stage Wk tail rows (sdv 2 + env 7) into LDS ----
    for (int i = tid; i < 900; i += NTHREADS) {
        *(f32x4*)&wk_s[i * 4] = *(const f32x4*)&Wk[100 * G4 + i * 4];
    }

    // ---- scaler constants ----
    float mean_r[7], istd_r[7];
    #pragma unroll
    for (int r = 0; r < 7; ++r) {
        mean_r[r] = sc_mean[r];
        istd_r[r] = 1.0f / sqrtf(sc_var[r]);
    }

    // ---- h1 = relu(z @ W1 + b1), staged into z_s as scratch ----
    {
        float zv[6];
        #pragma unroll
        for (int r = 0; r < 6; ++r) zv[r] = sampled_z[eg * 6 + r];
        for (int m = 0; m < 25; ++m) {
            const int c = q * 25 + m;
            float a = b1[c];
            #pragma unroll
            for (int r = 0; r < 6; ++r) a += zv[r] * W1[r * HDIM + c];
            z_s[e][c] = fmaxf(a, 0.0f);
        }
    }
    __syncthreads();

    // ---- proj = relu(h1 @ W2 + b2) -> h_s ; also the initial c state ----
    float c_reg[25];
    for (int m = 0; m < 25; ++m) {
        const int c = q * 25 + m;
        float a = b2[c];
        for (int k = 0; k < HDIM; ++k) a += z_s[e][k] * W2[k * HDIM + c];
        a = fmaxf(a, 0.0f);
        h_s[e][c] = a;
        c_reg[m] = a;
    }
    __syncthreads();

    // ---- gk = bl + proj @ Wk[0:100]  (constant over t) -> workspace ----
    f32x4 acc4[25];
    {
        #pragma unroll
        for (int m = 0; m < 25; ++m) acc4[m] = *(const f32x4*)&bl[j0 + 4 * m];
        for (int k = 0; k < HDIM; k += 4) {
            f32x4 hv = *(const f32x4*)&h_s[e][k];
            #pragma unroll
            for (int s = 0; s < 4; ++s) {
                const float hk = hv[s];
                const f32x4* wrow = (const f32x4*)&Wk[(k + s) * G4 + j0];
                #pragma unroll
                for (int m = 0; m < 25; ++m) acc4[m] += hk * wrow[m];
            }
        }
        #pragma unroll
        for (int m = 0; m < 25; ++m)
            *(f32x4*)&gk_ws[(size_t)eg * G4 + j0 + 4 * m] = acc4[m];
    }

    // ---- sequential LSTM over T steps ----
    float ego_v = 0.0f, ego_x = 0.0f, prev_act = 0.0f;
    const float bd0 = bd[0];

    for (int t = 0; t < T_STEPS; ++t) {
        // init acc with gk (x-constant part, includes bl)
        #pragma unroll
        for (int m = 0; m < 25; ++m)
            acc4[m] = *(const f32x4*)&gk_ws[(size_t)eg * G4 + j0 + 4 * m];

        // z += h @ Wr   (the dominant 100x400 matmul)
        for (int k = 0; k < HDIM; k += 4) {
            f32x4 hv = *(const f32x4*)&h_s[e][k];
            #pragma unroll
            for (int s = 0; s < 4; ++s) {
                const float hk = hv[s];
                const f32x4* wrow = (const f32x4*)&Wr[(k + s) * G4 + j0];
                #pragma unroll
                for (int m = 0; m < 25; ++m) acc4[m] += hk * wrow[m];
            }
        }

        // env features (computed redundantly by all 4 q-threads of e)
        const float* idm = &idm_s[(size_t)(eg * T_STEPS + t) * 12];
        f32x4 i0 = *(const f32x4*)&idm[0];
        f32x4 i1 = *(const f32x4*)&idm[4];
        f32x4 i2 = *(const f32x4*)&idm[8];
        f32x2 sd = *(const f32x2*)&sdv_acts[(size_t)(eg * T_STEPS + t) * 2];

        if (t == 0) {
            ego_v = i0[0];
            ego_x = i0[3];
        } else {
            ego_v = ego_v + prev_act * 0.1f;
            ego_x = ego_x + ego_v * 0.1f + 0.005f * prev_act;
        }
        const float f_veh_v = i0[1], m_veh_v = i0[2];
        const float f_glob_x = i1[0], m_glob_x = i1[1];
        const float ef_dv_t = i1[2], ef_dx_t = i1[3];
        const float em_dv_t = i2[0], em_dx_t = i2[1];
        const float f_ex = i2[2], m_ex = i2[3];
        const float ef_dx = (f_glob_x - ego_x) * f_ex + (1.0f - f_ex) * ef_dx_t;
        const float em_dx = (m_glob_x - ego_x) * m_ex + (1.0f - m_ex) * em_dx_t;
        const float ef_dv = (ego_v - f_veh_v) * f_ex + (1.0f - f_ex) * ef_dv_t;
        const float em_dv = (ego_v - m_veh_v) * m_ex + (1.0f - m_ex) * em_dv_t;

        float x9[9];
        x9[0] = sd[0];
        x9[1] = sd[1];
        x9[2] = (ego_v   - mean_r[0]) * istd_r[0];
        x9[3] = (f_veh_v - mean_r[1]) * istd_r[1];
        x9[4] = (m_veh_v - mean_r[2]) * istd_r[2];
        x9[5] = (ef_dv   - mean_r[3]) * istd_r[3];
        x9[6] = (ef_dx   - mean_r[4]) * istd_r[4];
        x9[7] = (em_dv   - mean_r[5]) * istd_r[5];
        x9[8] = (em_dx   - mean_r[6]) * istd_r[6];

        #pragma unroll
        for (int r = 0; r < 9; ++r) {
            const float xr = x9[r];
            const f32x4* wrow = (const f32x4*)&wk_s[r * G4 + j0];
            #pragma unroll
            for (int m = 0; m < 25; ++m) acc4[m] += xr * wrow[m];
        }

        // publish z for the gate exchange
        #pragma unroll
        for (int m = 0; m < 25; ++m)
            *(f32x4*)&z_s[e][j0 + 4 * m] = acc4[m];
        __syncthreads();

        // gates: thread (e,q) owns cols [q*25, q*25+25)
        float pact = 0.0f;
        const int c0 = q * 25;
        #pragma unroll
        for (int m = 0; m < 25; ++m) {
            const int col = c0 + m;
            const float iv = z_s[e][col];
            const float fv = z_s[e][100 + col];
            const float gv = z_s[e][200 + col];
            const float ov = z_s[e][300 + col];
            const float cc = sigf(fv) * c_reg[m] + sigf(iv) * tanh_fast(gv);
            const float hh = sigf(ov) * tanh_fast(cc);
            c_reg[m] = cc;
            h_s[e][col] = hh;
            pact += hh * Wd[col];
        }
        // reduce act over the 4-lane e-group (lanes e*4+q are adjacent)
        pact += __shfl_xor(pact, 1);
        pact += __shfl_xor(pact, 2);
        const float act = pact + bd0;
        if (q == 0) out[(size_t)eg * T_STEPS + t] = act;
        prev_act = act;
        __syncthreads();
    }
}

extern "C" void kernel_launch(void* const* d_in, const int* in_sizes, int n_in,
                              void* d_out, int out_size, void* d_ws, size_t ws_size,
                              hipStream_t stream) {
    const float* sampled_z = (const float*)d_in[0];
    const float* idm_s     = (const float*)d_in[1];
    const float* sdv_acts  = (const float*)d_in[2];
    const float* W1        = (const float*)d_in[3];
    const float* b1        = (const float*)d_in[4];
    const float* W2        = (const float*)d_in[5];
    const float* b2        = (const float*)d_in[6];
    const float* Wk        = (const float*)d_in[7];
    const float* Wr        = (const float*)d_in[8];
    const float* bl        = (const float*)d_in[9];
    const float* Wd        = (const float*)d_in[10];
    const float* bd        = (const float*)d_in[11];
    const float* sc_mean   = (const float*)d_in[12];
    const float* sc_var    = (const float*)d_in[13];

    float* out   = (float*)d_out;
    float* gk_ws = (float*)d_ws;   // needs B*400*4 = 26.2 MB

    dim3 grid(B_TOT / BT);   // 512 blocks
    dim3 block(NTHREADS);    // 128 threads = 32 elements * 4
    hipLaunchKernelGGL(fwdsim_kernel, grid, block, 0, stream,
                       sampled_z, idm_s, sdv_acts, W1, b1, W2, b2,
                       Wk, Wr, bl, Wd, bd, sc_mean, sc_var, out, gk_ws);
}

// Round 5
// 400.396 us; speedup vs baseline: 18.0868x; 18.0868x over previous
//
#include <hip/hip_runtime.h>

#define TS 40
#define BT 64
#define NT 256
#define MT 7      // m-tiles (16 rows) per wave ; M = 448 = 112 units * 4 gates
#define KC 4      // k-chunks of 32 ; K = 128 (100 h + 9 env + pad)
#define NTL 4     // n-tiles of 16 ; N = 64 batch

typedef short bf16x8 __attribute__((ext_vector_type(8)));
typedef float f32x4 __attribute__((ext_vector_type(4)));
typedef float f32x2 __attribute__((ext_vector_type(2)));

// LDS map (static): [0,114688) gkT fp32 swizzled ; init aliases: W2s@0(40000), h1s@40000(25600), projs@65600(25600)
// [114688,131072) H_hi bf16 ; [131072,147456) H_lo bf16 ; [147456,148480) part f32[4][64]
#define GKT_OFF   0
#define W2S_OFF   0
#define H1S_OFF   40000
#define PROJ_OFF  65600
#define HHI_OFF   114688
#define HLO_OFF   131072
#define PART_OFF  147456
#define SMEM_BYTES 148480

__device__ __forceinline__ unsigned short f2bf(float x) {
    unsigned u = __float_as_uint(x);
    unsigned r = u + 0x7fffu + ((u >> 16) & 1u);
    return (unsigned short)(r >> 16);
}
__device__ __forceinline__ float bf2f(unsigned short s) {
    return __uint_as_float(((unsigned)s) << 16);
}
__device__ __forceinline__ float sigf(float x) { return 1.0f / (1.0f + __expf(-x)); }
__device__ __forceinline__ float tanhf_(float x) { return 2.0f / (1.0f + __expf(-2.0f * x)) - 1.0f; }

// H (64 rows x 256B) : XOR-swizzle 16B chunks by (b&7)
__device__ __forceinline__ int hswz(int b, int byteoff) {
    return b * 256 + ((byteoff & ~15) ^ ((b & 7) << 4)) + (byteoff & 15);
}
// gkT (64 rows x 1792B = 112 chunks of 16B)
__device__ __forceinline__ int gswz(int b, int chunk) {
    return b * 1792 + ((chunk ^ (b & 7)) << 4);
}

__global__ void prep_kernel(const float* __restrict__ Wr, const float* __restrict__ Wk,
                            unsigned short* __restrict__ Am, unsigned short* __restrict__ Ah,
                            unsigned short* __restrict__ Al) {
    int gid = blockIdx.x * 256 + threadIdx.x;   // 448*128 = 57344
    int r = gid >> 7, k = gid & 127;
    int u = r >> 2, g = r & 3;
    float wm = 0.f, wkv = 0.f;
    if (u < 100) {
        int col = g * 100 + u;
        if (k < 100)      { wm = Wr[k * 400 + col]; wkv = Wk[k * 400 + col]; }
        else if (k < 109) { wm = Wk[k * 400 + col]; }
    }
    unsigned short hi = f2bf(wkv);
    Am[gid] = f2bf(wm);
    Ah[gid] = hi;
    Al[gid] = f2bf(wkv - bf2f(hi));
}

__global__ __launch_bounds__(NT, 1)
void fwdsim_kernel(const float* __restrict__ sampled_z,
                   const float* __restrict__ idm_s,
                   const float* __restrict__ sdv_acts,
                   const float* __restrict__ W1, const float* __restrict__ b1,
                   const float* __restrict__ W2, const float* __restrict__ b2,
                   const float* __restrict__ bl, const float* __restrict__ Wd,
                   const float* __restrict__ bd,
                   const float* __restrict__ sc_mean, const float* __restrict__ sc_var,
                   const unsigned short* __restrict__ Am,
                   const unsigned short* __restrict__ Ah,
                   const unsigned short* __restrict__ Al,
                   float* __restrict__ out) {
    __shared__ char sm[SMEM_BYTES];
    float* gkT  = (float*)(sm + GKT_OFF);
    char*  Hhi  = sm + HHI_OFF;
    char*  Hlo  = sm + HLO_OFF;
    float* part = (float*)(sm + PART_OFF);
    float* W2s  = (float*)(sm + W2S_OFF);
    float* h1s  = (float*)(sm + H1S_OFF);
    float* projs= (float*)(sm + PROJ_OFF);

    const int tid = threadIdx.x;
    const int w = tid >> 6, l = tid & 63, lb = l & 15, lg = l >> 4;
    const int blk = blockIdx.x;

    // ---------------- init: proj = relu(relu(z@W1+b1)@W2+b2) ----------------
    for (int i = tid; i < 2500; i += NT) ((f32x4*)W2s)[i] = ((const f32x4*)W2)[i];
    {
        const int e = tid >> 2, q = tid & 3;
        const int eg = blk * BT + e;
        float zv[6];
        #pragma unroll
        for (int r = 0; r < 6; ++r) zv[r] = sampled_z[eg * 6 + r];
        for (int m = 0; m < 25; ++m) {
            int c = q * 25 + m;
            float a = b1[c];
            #pragma unroll
            for (int r = 0; r < 6; ++r) a += zv[r] * W1[r * 100 + c];
            h1s[e * 100 + c] = fmaxf(a, 0.f);
        }
    }
    __syncthreads();
    {
        const int e = tid >> 2, q = tid & 3;
        for (int m = 0; m < 25; ++m) {
            int c = q * 25 + m;
            float a = b2[c];
            for (int k = 0; k < 100; ++k) a += h1s[e * 100 + k] * W2s[k * 100 + c];
            projs[e * 100 + c] = fmaxf(a, 0.f);
        }
    }
    __syncthreads();

    // ---------------- H init (h0 = proj, rows 100..127 = 0), c0, constants ----------------
    {
        const int b = tid >> 2, p = tid & 3;
        for (int kk = 0; kk < 32; ++kk) {
            int k = p * 32 + kk;
            float v = (k < 100) ? projs[b * 100 + k] : 0.f;
            unsigned short hi = f2bf(v);
            unsigned short lo = f2bf(v - bf2f(hi));
            int off = hswz(b, 2 * k);
            *(unsigned short*)(Hhi + off) = hi;
            *(unsigned short*)(Hlo + off) = lo;
        }
    }
    float c_st[MT][NTL];
    float wd_reg[MT];
    #pragma unroll
    for (int m = 0; m < MT; ++m) {
        const int u = w * 28 + m * 4 + lg;
        wd_reg[m] = (u < 100) ? Wd[u] : 0.f;
        #pragma unroll
        for (int n = 0; n < NTL; ++n) {
            const int b = n * 16 + lb;
            c_st[m][n] = (u < 100) ? projs[b * 100 + u] : 0.f;
        }
    }
    bf16x8 afr[MT][KC];
    #pragma unroll
    for (int m = 0; m < MT; ++m)
        #pragma unroll
        for (int kc = 0; kc < KC; ++kc) {
            const int row = w * 112 + m * 16 + lb;
            afr[m][kc] = *(const bf16x8*)(Am + row * 128 + kc * 32 + lg * 8);
        }
    float ms[7], is[7];
    #pragma unroll
    for (int r = 0; r < 7; ++r) { ms[r] = sc_mean[r]; is[r] = 1.0f / sqrtf(sc_var[r]); }
    const float bd0 = bd[0];
    const int b_env = w * 16 + lb;
    const size_t eg_env = (size_t)(blk * BT + b_env);
    f32x4 cur0 = {0,0,0,0}, cur1 = {0,0,0,0}, cur2 = {0,0,0,0};
    f32x2 curs = {0,0};
    f32x4 nxt0 = {0,0,0,0}, nxt1 = {0,0,0,0}, nxt2 = {0,0,0,0};
    f32x2 nxts = {0,0};
    if (lg == 0) {
        const float* ip = idm_s + (eg_env * TS + 0) * 12;
        cur0 = *(const f32x4*)ip; cur1 = *(const f32x4*)(ip + 4); cur2 = *(const f32x4*)(ip + 8);
        curs = *(const f32x2*)(sdv_acts + (eg_env * TS + 0) * 2);
    }
    __syncthreads();   // projs fully consumed; H ready

    // ---------------- gk = bl + WkT @ proj  (bf16x3 MFMA, fp32 result -> gkT LDS) ----------------
    {
        f32x4 acc[MT][NTL];
        #pragma unroll
        for (int m = 0; m < MT; ++m)
            #pragma unroll
            for (int n = 0; n < NTL; ++n) acc[m][n] = (f32x4){0.f, 0.f, 0.f, 0.f};
        for (int kc = 0; kc < KC; ++kc) {
            bf16x8 bhi[NTL], blo[NTL];
            #pragma unroll
            for (int n = 0; n < NTL; ++n) {
                const int b = n * 16 + lb;
                const int off = hswz(b, kc * 64 + lg * 16);
                bhi[n] = *(const bf16x8*)(Hhi + off);
                blo[n] = *(const bf16x8*)(Hlo + off);
            }
            #pragma unroll
            for (int m = 0; m < MT; ++m) {
                const int row = w * 112 + m * 16 + lb;
                bf16x8 ah = *(const bf16x8*)(Ah + row * 128 + kc * 32 + lg * 8);
                bf16x8 al = *(const bf16x8*)(Al + row * 128 + kc * 32 + lg * 8);
                #pragma unroll
                for (int n = 0; n < NTL; ++n) {
                    acc[m][n] = __builtin_amdgcn_mfma_f32_16x16x32_bf16(ah, bhi[n], acc[m][n], 0, 0, 0);
                    acc[m][n] = __builtin_amdgcn_mfma_f32_16x16x32_bf16(ah, blo[n], acc[m][n], 0, 0, 0);
                    acc[m][n] = __builtin_amdgcn_mfma_f32_16x16x32_bf16(al, bhi[n], acc[m][n], 0, 0, 0);
                }
            }
        }
        #pragma unroll
        for (int m = 0; m < MT; ++m) {
            float blv[4];
            #pragma unroll
            for (int j = 0; j < 4; ++j) {
                const int row = w * 112 + m * 16 + lg * 4 + j;
                const int u = row >> 2, g = row & 3;
                blv[j] = (u < 100) ? bl[g * 100 + u] : 0.f;
            }
            const int chunk = w * 28 + m * 4 + lg;
            #pragma unroll
            for (int n = 0; n < NTL; ++n) {
                const int b = n * 16 + lb;
                f32x4 v = acc[m][n];
                v[0] += blv[0]; v[1] += blv[1]; v[2] += blv[2]; v[3] += blv[3];
                *(f32x4*)((char*)gkT + gswz(b, chunk)) = v;
            }
        }
    }
    __syncthreads();   // gkT ready; all H reads of the gk GEMM done

    // ---------------- main 40-step recurrence ----------------
    float ego_v = 0.f, ego_x = 0.f, prev_act = 0.f;
    for (int t = 0; t < TS; ++t) {
        // A) env lanes: x9(t) -> H rows 100..108 ; prefetch idm(t+1)
        if (lg == 0) {
            if (t == 0) { ego_v = cur0[0]; ego_x = cur0[3]; }
            else {
                ego_v += prev_act * 0.1f;
                ego_x += ego_v * 0.1f + 0.005f * prev_act;
            }
            const float f_veh_v = cur0[1], m_veh_v = cur0[2];
            const float f_glob_x = cur1[0], m_glob_x = cur1[1];
            const float ef_dv_t = cur1[2], ef_dx_t = cur1[3];
            const float em_dv_t = cur2[0], em_dx_t = cur2[1];
            const float f_ex = cur2[2], m_ex = cur2[3];
            const float ef_dx = (f_glob_x - ego_x) * f_ex + (1.f - f_ex) * ef_dx_t;
            const float em_dx = (m_glob_x - ego_x) * m_ex + (1.f - m_ex) * em_dx_t;
            const float ef_dv = (ego_v - f_veh_v) * f_ex + (1.f - f_ex) * ef_dv_t;
            const float em_dv = (ego_v - m_veh_v) * m_ex + (1.f - m_ex) * em_dv_t;
            float x9[9];
            x9[0] = curs[0]; x9[1] = curs[1];
            x9[2] = (ego_v   - ms[0]) * is[0];
            x9[3] = (f_veh_v - ms[1]) * is[1];
            x9[4] = (m_veh_v - ms[2]) * is[2];
            x9[5] = (ef_dv   - ms[3]) * is[3];
            x9[6] = (ef_dx   - ms[4]) * is[4];
            x9[7] = (em_dv   - ms[5]) * is[5];
            x9[8] = (em_dx   - ms[6]) * is[6];
            #pragma unroll
            for (int r = 0; r < 9; ++r) {
                unsigned short hi = f2bf(x9[r]);
                const int off = hswz(b_env, 200 + 2 * r);
                *(unsigned short*)(Hhi + off) = hi;
                *(unsigned short*)(Hlo + off) = f2bf(x9[r] - bf2f(hi));
            }
            if (t < TS - 1) {
                const float* ip = idm_s + (eg_env * TS + t + 1) * 12;
                nxt0 = *(const f32x4*)ip; nxt1 = *(const f32x4*)(ip + 4); nxt2 = *(const f32x4*)(ip + 8);
                nxts = *(const f32x2*)(sdv_acts + (eg_env * TS + t + 1) * 2);
            }
        }
        __syncthreads();   // B: x9+h visible

        // C) z^T = gk + W_combT @ [h_hi+h_lo ; x9]
        f32x4 acc[MT][NTL];
        #pragma unroll
        for (int m = 0; m < MT; ++m) {
            const int chunk = w * 28 + m * 4 + lg;
            #pragma unroll
            for (int n = 0; n < NTL; ++n)
                acc[m][n] = *(const f32x4*)((const char*)gkT + gswz(n * 16 + lb, chunk));
        }
        #pragma unroll
        for (int kc = 0; kc < KC; ++kc) {
            bf16x8 bhi[NTL], blo[NTL];
            #pragma unroll
            for (int n = 0; n < NTL; ++n) {
                const int b = n * 16 + lb;
                const int off = hswz(b, kc * 64 + lg * 16);
                bhi[n] = *(const bf16x8*)(Hhi + off);
                blo[n] = *(const bf16x8*)(Hlo + off);
            }
            #pragma unroll
            for (int m = 0; m < MT; ++m) {
                #pragma unroll
                for (int n = 0; n < NTL; ++n) {
                    acc[m][n] = __builtin_amdgcn_mfma_f32_16x16x32_bf16(afr[m][kc], bhi[n], acc[m][n], 0, 0, 0);
                    acc[m][n] = __builtin_amdgcn_mfma_f32_16x16x32_bf16(afr[m][kc], blo[n], acc[m][n], 0, 0, 0);
                }
            }
        }
        __syncthreads();   // D: all H reads done before h(t+1) writes

        // E) gates in-register; h -> LDS ; act partials
        float pact[NTL] = {0.f, 0.f, 0.f, 0.f};
        #pragma unroll
        for (int m = 0; m < MT; ++m) {
            const int u = w * 28 + m * 4 + lg;
            #pragma unroll
            for (int n = 0; n < NTL; ++n) {
                const int b = n * 16 + lb;
                f32x4 z = acc[m][n];
                const float cc = sigf(z[1]) * c_st[m][n] + sigf(z[0]) * tanhf_(z[2]);
                const float hh = sigf(z[3]) * tanhf_(cc);
                c_st[m][n] = cc;
                pact[n] += hh * wd_reg[m];
                if (u < 100) {
                    unsigned short hi = f2bf(hh);
                    const int off = hswz(b, 2 * u);
                    *(unsigned short*)(Hhi + off) = hi;
                    *(unsigned short*)(Hlo + off) = f2bf(hh - bf2f(hi));
                }
            }
        }
        #pragma unroll
        for (int n = 0; n < NTL; ++n) {
            float p = pact[n];
            p += __shfl_xor(p, 16);
            p += __shfl_xor(p, 32);
            if (l < 16) part[w * 64 + n * 16 + l] = p;
        }
        __syncthreads();   // F: part + h visible

        // G) act = sum(part) + bd ; output ; advance env prefetch
        if (lg == 0) {
            const float act = part[b_env] + part[64 + b_env] + part[128 + b_env] + part[192 + b_env] + bd0;
            out[eg_env * TS + t] = act;
            prev_act = act;
            if (t < TS - 1) { cur0 = nxt0; cur1 = nxt1; cur2 = nxt2; curs = nxts; }
        }
    }
}

extern "C" void kernel_launch(void* const* d_in, const int* in_sizes, int n_in,
                              void* d_out, int out_size, void* d_ws, size_t ws_size,
                              hipStream_t stream) {
    const float* sampled_z = (const float*)d_in[0];
    const float* idm_s     = (const float*)d_in[1];
    const float* sdv_acts  = (const float*)d_in[2];
    const float* W1        = (const float*)d_in[3];
    const float* b1        = (const float*)d_in[4];
    const float* W2        = (const float*)d_in[5];
    const float* b2        = (const float*)d_in[6];
    const float* Wk        = (const float*)d_in[7];
    const float* Wr        = (const float*)d_in[8];
    const float* bl        = (const float*)d_in[9];
    const float* Wd        = (const float*)d_in[10];
    const float* bd        = (const float*)d_in[11];
    const float* sc_mean   = (const float*)d_in[12];
    const float* sc_var    = (const float*)d_in[13];
    float* out = (float*)d_out;

    unsigned short* Am = (unsigned short*)d_ws;       // [448][128] bf16
    unsigned short* Ah = Am + 448 * 128;              // Wk-proj hi
    unsigned short* Al = Ah + 448 * 128;              // Wk-proj lo

    hipLaunchKernelGGL(prep_kernel, dim3(224), dim3(256), 0, stream, Wr, Wk, Am, Ah, Al);
    hipLaunchKernelGGL(fwdsim_kernel, dim3(16384 / BT), dim3(NT), 0, stream,
                       sampled_z, idm_s, sdv_acts, W1, b1, W2, b2, bl, Wd, bd,
                       sc_mean, sc_var, Am, Ah, Al, out);
}